// Round 9
// baseline (327.267 us; speedup 1.0000x reference)
//
#include <hip/hip_runtime.h>
#include <hip/hip_cooperative_groups.h>
#include <stdint.h>

namespace cg = cooperative_groups;

#define HV 384
#define WV 384
#define HF 96
#define WF 96
#define NC 128
#define NB 32
#define NSTORM 50
#define TFRAMES 12
#define MIN_INT 0.3f

// peak tile geometry
#define TW 64
#define TH 32
#define GX (WV / TW)          // 6
#define GY (HV / TH)          // 12
#define GT (GX * GY)          // 72 tiles per batch
#define NTILE (GT * NB)       // 2304
#define LCAP 256

// selection
#define CCAP 1024
// projection
#define SPB 5
#define NPROJ (NB * (NSTORM / SPB))   // 320

// cooperative grid
#define NBLK 768              // 3 tiles per block in phase 1

// LDS overlay offsets (bytes); total 23296
#define SM_BYTES 23296

__device__ __forceinline__ int reflect_idx(int g, int n) {
    if (g < 0) return -g - 1;
    if (g >= n) return 2 * n - 1 - g;
    return g;
}

// ---- slow scalar peak predicate, only on the dead (<50 peaks) fallback path
__device__ __forceinline__ bool is_peak(const float* __restrict__ vb, int p) {
    int i = p / WV, j = p % WV;
    float v = vb[p];
    if (!(v > MIN_INT)) return false;
    for (int dr = -4; dr <= 3; ++dr) {
        const float* row = vb + reflect_idx(i + dr, HV) * WV;
        for (int dc = -4; dc <= 3; ++dc)
            if (row[reflect_idx(j + dc, WV)] > v) return false;
    }
    return true;
}

// ================= phase 1: peak detection for one 64x32 tile ==============
__device__ void do_peak_tile(const float* __restrict__ vil,
                             uint64_t* __restrict__ cand,
                             int* __restrict__ tcnt,
                             unsigned char* smem, int T) {
    float (*A)[TW + 8] = (float (*)[TW + 8])smem;            // 39x72 = 11232 B
    float (*Bm)[TW]    = (float (*)[TW])(smem + 11232);      // 39x64 = 9984 B
    uint64_t* lkeys    = (uint64_t*)(smem + 21216);          // 2048 B
    int* lcnt          = (int*)(smem + 23264);

    int b = T / GT, tile = T % GT;
    int by = tile / GX, bx = tile % GX;
    int tx0 = bx * TW, ty0 = by * TH;
    int tid = threadIdx.x;                 // 256
    const float* vb = vil + ((size_t)b * TFRAMES + (TFRAMES - 1)) * (HV * WV);

    __syncthreads();                       // protect smem reuse across tiles
    if (tid == 0) *lcnt = 0;

    // float4 staging; row reflect is pointer-only, keeps 16B alignment.
    int c0   = (bx == 0) ? 0 : tx0 - 4;
    int nf4  = (bx == 0 || bx == GX - 1) ? 17 : 18;
    int aoff = c0 - (tx0 - 4);                        // 0 or 4
    for (int k = tid; k < (TH + 7) * nf4; k += 256) {
        int r = k / nf4, q = k - r * nf4;
        int gr = reflect_idx(ty0 + r - 4, HV);
        float4 vv = *(const float4*)(vb + (size_t)gr * WV + c0 + 4 * q);
        *(float4*)&A[r][aoff + 4 * q] = vv;
    }
    int nl = aoff;
    int rstart = aoff + 4 * nf4;
    int nr = 71 - rstart; if (nr < 0) nr = 0;
    int ns = nl + nr;
    if (ns) for (int k = tid; k < (TH + 7) * ns; k += 256) {
        int r = k / ns, s = k - r * ns;
        int c = (s < nl) ? s : rstart + (s - nl);
        int gr = reflect_idx(ty0 + r - 4, HV);
        int gc = reflect_idx(tx0 + c - 4, WV);
        A[r][c] = vb[(size_t)gr * WV + gc];
    }
    __syncthreads();

    // horizontal: Bm[r][c] = max(A[r][c..c+7])
    for (int k = tid; k < (TH + 7) * TW; k += 256) {
        int r = k / TW, c = k % TW;
        float m = A[r][c];
        #pragma unroll
        for (int d = 1; d < 8; ++d) m = fmaxf(m, A[r][c + d]);
        Bm[r][c] = m;
    }
    __syncthreads();

    // vertical + predicate
    for (int k = tid; k < TH * TW; k += 256) {
        int r = k / TW, c = k % TW;
        float v = A[r + 4][c + 4];
        if (v > MIN_INT) {
            float m = Bm[r][c];
            #pragma unroll
            for (int d = 1; d < 8; ++d) m = fmaxf(m, Bm[r + d][c]);
            if (m <= v) {                  // window max == v -> peak
                int p = (ty0 + r) * WV + (tx0 + c);
                uint64_t key = ((uint64_t)__float_as_uint(v) << 32)
                             | (uint64_t)(0xFFFFFFFFu - (uint32_t)p);
                int pos = atomicAdd(lcnt, 1);         // LDS atomic only
                if (pos < LCAP) lkeys[pos] = key;
            }
        }
    }
    __syncthreads();

    int take = *lcnt < LCAP ? *lcnt : LCAP;
    if (tid == 0) tcnt[b * GT + tile] = take;
    uint64_t* dst = cand + (size_t)(b * GT + tile) * LCAP;
    for (int k = tid; k < take; k += 256) dst[k] = lkeys[k];
}

// ================= phase 2: top-50 via histogram (one batch) ===============
__device__ void do_select(const uint64_t* __restrict__ cand,
                          const int* __restrict__ tcnt,
                          const float* __restrict__ vil,
                          int* __restrict__ sel_idx,
                          int* __restrict__ sel_valid,
                          float* __restrict__ out,
                          unsigned char* smem, int b) {
    uint64_t* coll   = (uint64_t*)smem;                 // 8192 B
    int* hist        = (int*)(smem + 8192);             // 1024
    int* rss         = (int*)(smem + 9216);             // 1024
    int* sc          = (int*)(smem + 10240);            // 512
    int* offs        = (int*)(smem + 10752);            // 292 (+pad)
    int* sel_idx_s   = (int*)(smem + 11072);            // 200
    int* sel_valid_s = (int*)(smem + 11272);            // 200
    uint64_t* wred   = (uint64_t*)(smem + 11472);       // 32
    uint64_t* bcast  = (uint64_t*)(smem + 11504);       // 8
    int* jstar_s     = (int*)(smem + 11512);
    int* ccnt        = (int*)(smem + 11516);

    int tid = threadIdx.x;                     // 256
    const uint64_t* cb = cand + (size_t)b * GT * LCAP;

    // scan of 72 tile counts
    int cval = (tid < GT) ? tcnt[b * GT + tid] : 0;
    if (tid < 128) sc[tid] = cval;
    hist[tid] = 0;
    if (tid == 0) *ccnt = 0;
    __syncthreads();
    #pragma unroll
    for (int off = 1; off < 128; off <<= 1) {
        int v = 0;
        if (tid < 128 && tid >= off) v = sc[tid - off];
        __syncthreads();
        if (tid < 128) sc[tid] += v;
        __syncthreads();
    }
    if (tid == 0) offs[0] = 0;
    if (tid < GT) offs[tid + 1] = sc[tid];
    __syncthreads();
    int n = offs[GT];
    int target = n < NSTORM ? n : NSTORM;

    if (n > 0) {
        // pass 1: histogram of top-16-bit value bins
        for (int gi = tid; gi < n; gi += 256) {
            int lo = 0, hi = GT;
            while (hi - lo > 1) { int mid = (lo + hi) >> 1;
                                  if (offs[mid] <= gi) lo = mid; else hi = mid; }
            uint64_t key = cb[(size_t)lo * LCAP + (gi - offs[lo])];
            int bin = (int)(uint32_t)((key >> 48)) - 0x3E99;
            bin = (bin < 0) ? 0 : (bin > 255 ? 255 : bin);
            atomicAdd(&hist[bin], 1);
        }
        __syncthreads();
        rss[tid] = hist[255 - tid];
        __syncthreads();
        #pragma unroll
        for (int off = 1; off < 256; off <<= 1) {
            int v = (tid >= off) ? rss[tid - off] : 0;
            __syncthreads();
            rss[tid] += v;
            __syncthreads();
        }
        {   // j* = max j with S[j] >= target
            int S_j  = rss[255 - tid];
            int S_j1 = (tid == 255) ? 0 : rss[254 - tid];
            if (S_j >= target && S_j1 < target) *jstar_s = tid;
        }
        __syncthreads();
        int jstar = *jstar_s;
        // pass 2: collect keys in bins >= j*
        for (int gi = tid; gi < n; gi += 256) {
            int lo = 0, hi = GT;
            while (hi - lo > 1) { int mid = (lo + hi) >> 1;
                                  if (offs[mid] <= gi) lo = mid; else hi = mid; }
            uint64_t key = cb[(size_t)lo * LCAP + (gi - offs[lo])];
            int bin = (int)(uint32_t)((key >> 48)) - 0x3E99;
            bin = (bin < 0) ? 0 : (bin > 255 ? 255 : bin);
            if (bin >= jstar) {
                int pos = atomicAdd(ccnt, 1);
                if (pos < CCAP) coll[pos] = key;
            }
        }
        __syncthreads();
        int m = *ccnt < CCAP ? *ccnt : CCAP;

        if (*ccnt <= CCAP) {
            // rank each collected key (keys unique -> unique ranks)
            for (int i = tid; i < m; i += 256) {
                uint64_t ki = coll[i];
                int r = 0;
                for (int j = 0; j < m; ++j) r += (coll[j] > ki);
                if (r < target) {
                    sel_idx_s[r] = (int)(~(uint32_t)(ki & 0xFFFFFFFFu));
                    sel_valid_s[r] = 1;
                }
            }
        } else {
            // dead safety path (collect overflow): iterative rescan
            uint64_t prev = ~0ull;
            for (int t = 0; t < target; ++t) {
                uint64_t best = 0;
                for (int gi = tid; gi < n; gi += 256) {
                    int lo = 0, hi = GT;
                    while (hi - lo > 1) { int mid = (lo + hi) >> 1;
                                          if (offs[mid] <= gi) lo = mid; else hi = mid; }
                    uint64_t key = cb[(size_t)lo * LCAP + (gi - offs[lo])];
                    if (key < prev && key > best) best = key;
                }
                #pragma unroll
                for (int off = 32; off > 0; off >>= 1) {
                    uint64_t o = __shfl_xor(best, off);
                    if (o > best) best = o;
                }
                if ((tid & 63) == 0) wred[tid >> 6] = best;
                __syncthreads();
                if (tid == 0) {
                    uint64_t w = wred[0];
                    #pragma unroll
                    for (int i = 1; i < 4; ++i) if (wred[i] > w) w = wred[i];
                    *bcast = w;
                    sel_idx_s[t] = (int)(~(uint32_t)(w & 0xFFFFFFFFu));
                    sel_valid_s[t] = 1;
                }
                __syncthreads();
                prev = *bcast;
            }
        }
    }
    __syncthreads();

    // dead fallback: <50 peaks -> ascending non-peak indices; none -> center
    if (tid == 0 && target < NSTORM) {
        const float* vb = vil + ((size_t)b * TFRAMES + (TFRAMES - 1)) * (HV * WV);
        int f = 0;
        for (int t = target; t < NSTORM; ++t) {
            while (f < HV * WV && is_peak(vb, f)) ++f;
            sel_idx_s[t] = f; sel_valid_s[t] = 0; ++f;
        }
        if (n == 0) { sel_idx_s[0] = (HV / 2) * WV + (WV / 2); sel_valid_s[0] = 1; }
    }
    __syncthreads();

    if (tid < NSTORM) {
        int idx = sel_idx_s[tid], vld = sel_valid_s[tid];
        sel_idx[b * NSTORM + tid] = idx;
        sel_valid[b * NSTORM + tid] = vld;
        int y = idx / WV, x = idx % WV;
        int yf = y >> 2; if (yf > HF - 1) yf = HF - 1;
        int xf = x >> 2; if (xf > WF - 1) xf = WF - 1;
        float* pos_out   = out + (size_t)NB * NSTORM * NC;
        float* valid_out = pos_out + (size_t)NB * NSTORM * 2;
        pos_out[(b * NSTORM + tid) * 2 + 0] = (float)yf;
        pos_out[(b * NSTORM + tid) * 2 + 1] = (float)xf;
        valid_out[b * NSTORM + tid] = vld ? 1.f : 0.f;
    }
}

// ================= phase 3: gather + matvec for 5 storms ===================
__device__ void do_project(const float* __restrict__ features,
                           const float* __restrict__ proj_w,
                           const float* __restrict__ proj_b,
                           const int* __restrict__ sel_idx,
                           const int* __restrict__ sel_valid,
                           float* __restrict__ out,
                           unsigned char* smem, int unit) {
    float (*g)[NC] = (float (*)[NC])smem;              // 2560 B
    int* idxs = (int*)(smem + 2560);
    int* vlds = (int*)(smem + 2584);

    int b = unit / (NSTORM / SPB);
    int grp = unit % (NSTORM / SPB);
    int tid = threadIdx.x;                 // 256 (128 used for matvec)

    if (tid < SPB) {
        int m = grp * SPB + tid;
        idxs[tid] = sel_idx[b * NSTORM + m];
        vlds[tid] = sel_valid[b * NSTORM + m];
    }
    __syncthreads();

    for (int q = tid; q < SPB * NC; q += 256) {
        int s = q >> 7, c = q & 127;
        int idx = idxs[s];
        int y = idx / WV, x = idx % WV;
        int yf = y >> 2; if (yf > HF - 1) yf = HF - 1;
        int xf = x >> 2; if (xf > WF - 1) xf = WF - 1;
        g[s][c] = features[((size_t)b * NC + c) * (HF * WF) + yf * WF + xf];
    }
    __syncthreads();

    if (tid < NC) {
        int d = tid;
        const float4* w4 = (const float4*)(proj_w + (size_t)d * NC);
        float acc[SPB] = {0.f, 0.f, 0.f, 0.f, 0.f};
        for (int q = 0; q < 32; ++q) {
            float4 wv = w4[q];
            #pragma unroll
            for (int s = 0; s < SPB; ++s) {
                float4 gv = *(const float4*)&g[s][4 * q];
                acc[s] += gv.x * wv.x;
                acc[s] += gv.y * wv.y;
                acc[s] += gv.z * wv.z;
                acc[s] += gv.w * wv.w;
            }
        }
        float bias = proj_b[d];
        #pragma unroll
        for (int s = 0; s < SPB; ++s) {
            int m = grp * SPB + s;
            out[((size_t)b * NSTORM + m) * NC + d] = vlds[s] ? (acc[s] + bias) : 0.f;
        }
    }
}

// ================= fused cooperative kernel ================================
__global__ __launch_bounds__(256, 3)
void fused_kernel(const float* __restrict__ vil,
                  uint64_t* __restrict__ cand,
                  int* __restrict__ tcnt,
                  const float* __restrict__ features,
                  const float* __restrict__ proj_w,
                  const float* __restrict__ proj_b,
                  int* __restrict__ sel_idx,
                  int* __restrict__ sel_valid,
                  float* __restrict__ out) {
    __shared__ __align__(16) unsigned char smem[SM_BYTES];
    int blk = blockIdx.x;

    #pragma unroll
    for (int i = 0; i < NTILE / NBLK; ++i)
        do_peak_tile(vil, cand, tcnt, smem, blk * (NTILE / NBLK) + i);

    __threadfence();
    cg::this_grid().sync();

    if (blk < NB)
        do_select(cand, tcnt, vil, sel_idx, sel_valid, out, smem, blk);

    __threadfence();
    cg::this_grid().sync();

    if (blk < NPROJ)
        do_project(features, proj_w, proj_b, sel_idx, sel_valid, out, smem, blk);
}

// ================= standalone fallback kernels =============================
__global__ void peak_kernel(const float* __restrict__ vil,
                            uint64_t* __restrict__ cand,
                            int* __restrict__ tcnt) {
    __shared__ __align__(16) unsigned char smem[SM_BYTES];
    do_peak_tile(vil, cand, tcnt, smem, blockIdx.x);
}

__global__ void select_kernel(const uint64_t* __restrict__ cand,
                              const int* __restrict__ tcnt,
                              const float* __restrict__ vil,
                              int* __restrict__ sel_idx,
                              int* __restrict__ sel_valid,
                              float* __restrict__ out) {
    __shared__ __align__(16) unsigned char smem[SM_BYTES];
    do_select(cand, tcnt, vil, sel_idx, sel_valid, out, smem, blockIdx.x);
}

__global__ void project_kernel(const float* __restrict__ features,
                               const float* __restrict__ proj_w,
                               const float* __restrict__ proj_b,
                               const int* __restrict__ sel_idx,
                               const int* __restrict__ sel_valid,
                               float* __restrict__ out) {
    __shared__ __align__(16) unsigned char smem[SM_BYTES];
    do_project(features, proj_w, proj_b, sel_idx, sel_valid, out, smem, blockIdx.x);
}

extern "C" void kernel_launch(void* const* d_in, const int* in_sizes, int n_in,
                              void* d_out, int out_size, void* d_ws, size_t ws_size,
                              hipStream_t stream) {
    const float* features = (const float*)d_in[0];
    const float* vil      = (const float*)d_in[1];
    const float* proj_w   = (const float*)d_in[2];
    const float* proj_b   = (const float*)d_in[3];
    float* out = (float*)d_out;

    uint8_t* ws = (uint8_t*)d_ws;
    int* tcnt      = (int*)ws;                        // 2304 ints, all written
    int* sel_idx   = (int*)(ws + 16384);
    int* sel_valid = (int*)(ws + 16384 + NB * NSTORM * sizeof(int));
    uint64_t* cand = (uint64_t*)(ws + 32768);         // 2304*256 u64 = 4.7 MB

    void* args[] = {(void*)&vil, (void*)&cand, (void*)&tcnt, (void*)&features,
                    (void*)&proj_w, (void*)&proj_b, (void*)&sel_idx,
                    (void*)&sel_valid, (void*)&out};
    hipError_t e = hipLaunchCooperativeKernel((const void*)fused_kernel,
                                              dim3(NBLK), dim3(256), args, 0, stream);
    if (e != hipSuccess) {
        // fallback: 3-dispatch path (identical phase bodies)
        peak_kernel<<<NTILE, 256, 0, stream>>>(vil, cand, tcnt);
        select_kernel<<<NB, 256, 0, stream>>>(cand, tcnt, vil, sel_idx, sel_valid, out);
        project_kernel<<<NPROJ, 256, 0, stream>>>(features, proj_w, proj_b,
                                                  sel_idx, sel_valid, out);
    }
}

// Round 10
// 211.809 us; speedup vs baseline: 1.5451x; 1.5451x over previous
//
#include <hip/hip_runtime.h>
#include <stdint.h>

#define HV 384
#define WV 384
#define HF 96
#define WF 96
#define NC 128
#define NB 32
#define NSTORM 50
#define TFRAMES 12
#define MIN_INT 0.3f

// peak tile geometry
#define TW 64
#define TH 32
#define GX (WV / TW)          // 6
#define GY (HV / TH)          // 12
#define GT (GX * GY)          // 72 tiles per batch
#define LCAP 256              // >= provable max peaks per tile (~153)

// selection
#define CCAP 1024             // collect buffer (expected ~80 used)

__device__ __forceinline__ int reflect_idx(int g, int n) {
    if (g < 0) return -g - 1;
    if (g >= n) return 2 * n - 1 - g;
    return g;
}

// ---- slow scalar peak predicate, used only on the dead fallback path
__device__ __forceinline__ bool is_peak(const float* __restrict__ vb, int p) {
    int i = p / WV, j = p % WV;
    float v = vb[p];
    if (!(v > MIN_INT)) return false;
    for (int dr = -4; dr <= 3; ++dr) {
        const float* row = vb + reflect_idx(i + dr, HV) * WV;
        for (int dc = -4; dc <= 3; ++dc)
            if (row[reflect_idx(j + dc, WV)] > v) return false;
    }
    return true;
}

// ---- kernel 1: separable 8x8 max filter on LDS tiles; float4 staging;
// per-tile candidate slots (no global atomics, no memset — every tcnt slot
// is written every launch). key = (float_bits(v) << 32) | ~idx — strict
// total order -> deterministic selection regardless of compaction order.
__global__ void peak_kernel(const float* __restrict__ vil,
                            uint64_t* __restrict__ cand,
                            int* __restrict__ tcnt) {
    __shared__ __align__(16) float A[TH + 7][TW + 8];  // tile + halo
    __shared__ float Bm[TH + 7][TW];                   // horizontal max
    __shared__ uint64_t lkeys[LCAP];
    __shared__ int lcnt;

    int b = blockIdx.z, bx = blockIdx.x;
    int tx0 = bx * TW, ty0 = blockIdx.y * TH;
    int tile = blockIdx.y * GX + bx;
    int tid = threadIdx.x;                 // 256 threads
    const float* vb = vil + ((size_t)b * TFRAMES + (TFRAMES - 1)) * (HV * WV);

    if (tid == 0) lcnt = 0;

    // float4 staging; row reflect is pointer-only, keeps 16B alignment.
    int c0   = (bx == 0) ? 0 : tx0 - 4;               // multiple of 4
    int nf4  = (bx == 0 || bx == GX - 1) ? 17 : 18;
    int aoff = c0 - (tx0 - 4);                        // 0 or 4
    for (int k = tid; k < (TH + 7) * nf4; k += 256) {
        int r = k / nf4, q = k - r * nf4;
        int gr = reflect_idx(ty0 + r - 4, HV);
        float4 vv = *(const float4*)(vb + (size_t)gr * WV + c0 + 4 * q);
        *(float4*)&A[r][aoff + 4 * q] = vv;
    }
    int nl = aoff;
    int rstart = aoff + 4 * nf4;
    int nr = 71 - rstart; if (nr < 0) nr = 0;
    int ns = nl + nr;
    if (ns) for (int k = tid; k < (TH + 7) * ns; k += 256) {
        int r = k / ns, s = k - r * ns;
        int c = (s < nl) ? s : rstart + (s - nl);
        int gr = reflect_idx(ty0 + r - 4, HV);
        int gc = reflect_idx(tx0 + c - 4, WV);
        A[r][c] = vb[(size_t)gr * WV + gc];
    }
    __syncthreads();

    // horizontal: Bm[r][c] = max(A[r][c..c+7])
    for (int k = tid; k < (TH + 7) * TW; k += 256) {
        int r = k / TW, c = k % TW;
        float m = A[r][c];
        #pragma unroll
        for (int d = 1; d < 8; ++d) m = fmaxf(m, A[r][c + d]);
        Bm[r][c] = m;
    }
    __syncthreads();

    // vertical + predicate
    for (int k = tid; k < TH * TW; k += 256) {
        int r = k / TW, c = k % TW;
        float v = A[r + 4][c + 4];
        if (v > MIN_INT) {
            float m = Bm[r][c];
            #pragma unroll
            for (int d = 1; d < 8; ++d) m = fmaxf(m, Bm[r + d][c]);
            if (m <= v) {                  // window max == v -> peak
                int p = (ty0 + r) * WV + (tx0 + c);
                uint64_t key = ((uint64_t)__float_as_uint(v) << 32)
                             | (uint64_t)(0xFFFFFFFFu - (uint32_t)p);
                int pos = atomicAdd(&lcnt, 1);        // LDS atomic only
                if (pos < LCAP) lkeys[pos] = key;
            }
        }
    }
    __syncthreads();

    int take = lcnt < LCAP ? lcnt : LCAP;
    if (tid == 0) tcnt[b * GT + tile] = take;
    uint64_t* dst = cand + (size_t)(b * GT + tile) * LCAP;
    for (int k = tid; k < take; k += 256) dst[k] = lkeys[k];
}

// ---- kernel 2 (fused): per batch — histogram top-50 select, then gather
// all 50 feature columns into LDS and do the 128x128 projection in-block.
// 32 blocks x 256 threads. Select results never leave LDS.
__global__ void select_project_kernel(const uint64_t* __restrict__ cand,
                                      const int* __restrict__ tcnt,
                                      const float* __restrict__ vil,
                                      const float* __restrict__ features,
                                      const float* __restrict__ proj_w,
                                      const float* __restrict__ proj_b,
                                      float* __restrict__ out) {
    __shared__ float g[NSTORM][NC];            // 25.6 KB
    __shared__ uint64_t coll[CCAP];            // 8 KB
    __shared__ int hist[256];
    __shared__ int rss[256];                   // reversed suffix scan
    __shared__ int sc[128];
    __shared__ int offs[GT + 1];
    __shared__ int sel_idx_s[NSTORM];
    __shared__ int sel_valid_s[NSTORM];
    __shared__ int lin_s[NSTORM];
    __shared__ int jstar_s, ccnt;
    __shared__ uint64_t wred[4];
    __shared__ uint64_t bcast;

    int b = blockIdx.x;
    int tid = threadIdx.x;                     // 256
    const uint64_t* cb = cand + (size_t)b * GT * LCAP;

    // ---- select: scan of 72 tile counts
    int cval = (tid < GT) ? tcnt[b * GT + tid] : 0;
    if (tid < 128) sc[tid] = cval;
    hist[tid] = 0;
    if (tid == 0) ccnt = 0;
    __syncthreads();
    #pragma unroll
    for (int off = 1; off < 128; off <<= 1) {
        int v = 0;
        if (tid < 128 && tid >= off) v = sc[tid - off];
        __syncthreads();
        if (tid < 128) sc[tid] += v;
        __syncthreads();
    }
    if (tid == 0) offs[0] = 0;
    if (tid < GT) offs[tid + 1] = sc[tid];
    __syncthreads();
    int n = offs[GT];
    int target = n < NSTORM ? n : NSTORM;

    if (n > 0) {
        // pass 1: histogram of top-16-bit value bins (monotone in key)
        for (int gi = tid; gi < n; gi += 256) {
            int lo = 0, hi = GT;
            while (hi - lo > 1) { int mid = (lo + hi) >> 1;
                                  if (offs[mid] <= gi) lo = mid; else hi = mid; }
            uint64_t key = cb[(size_t)lo * LCAP + (gi - offs[lo])];
            int bin = (int)(uint32_t)((key >> 48)) - 0x3E99;
            bin = (bin < 0) ? 0 : (bin > 255 ? 255 : bin);
            atomicAdd(&hist[bin], 1);
        }
        __syncthreads();
        rss[tid] = hist[255 - tid];
        __syncthreads();
        #pragma unroll
        for (int off = 1; off < 256; off <<= 1) {
            int v = (tid >= off) ? rss[tid - off] : 0;
            __syncthreads();
            rss[tid] += v;
            __syncthreads();
        }
        {   // j* = max j with S[j] >= target
            int S_j  = rss[255 - tid];
            int S_j1 = (tid == 255) ? 0 : rss[254 - tid];
            if (S_j >= target && S_j1 < target) jstar_s = tid;
        }
        __syncthreads();
        int jstar = jstar_s;
        // pass 2: collect keys in bins >= j* (expected ~80)
        for (int gi = tid; gi < n; gi += 256) {
            int lo = 0, hi = GT;
            while (hi - lo > 1) { int mid = (lo + hi) >> 1;
                                  if (offs[mid] <= gi) lo = mid; else hi = mid; }
            uint64_t key = cb[(size_t)lo * LCAP + (gi - offs[lo])];
            int bin = (int)(uint32_t)((key >> 48)) - 0x3E99;
            bin = (bin < 0) ? 0 : (bin > 255 ? 255 : bin);
            if (bin >= jstar) {
                int pos = atomicAdd(&ccnt, 1);
                if (pos < CCAP) coll[pos] = key;
            }
        }
        __syncthreads();
        int m = ccnt < CCAP ? ccnt : CCAP;

        if (ccnt <= CCAP) {
            // rank each collected key (keys unique -> unique ranks)
            for (int i = tid; i < m; i += 256) {
                uint64_t ki = coll[i];
                int r = 0;
                for (int j = 0; j < m; ++j) r += (coll[j] > ki);
                if (r < target) {
                    sel_idx_s[r] = (int)(~(uint32_t)(ki & 0xFFFFFFFFu));
                    sel_valid_s[r] = 1;
                }
            }
        } else {
            // dead safety path (collect overflow): iterative rescan
            uint64_t prev = ~0ull;
            for (int t = 0; t < target; ++t) {
                uint64_t best = 0;
                for (int gi = tid; gi < n; gi += 256) {
                    int lo = 0, hi = GT;
                    while (hi - lo > 1) { int mid = (lo + hi) >> 1;
                                          if (offs[mid] <= gi) lo = mid; else hi = mid; }
                    uint64_t key = cb[(size_t)lo * LCAP + (gi - offs[lo])];
                    if (key < prev && key > best) best = key;
                }
                #pragma unroll
                for (int off = 32; off > 0; off >>= 1) {
                    uint64_t o = __shfl_xor(best, off);
                    if (o > best) best = o;
                }
                if ((tid & 63) == 0) wred[tid >> 6] = best;
                __syncthreads();
                if (tid == 0) {
                    uint64_t w = wred[0];
                    #pragma unroll
                    for (int i = 1; i < 4; ++i) if (wred[i] > w) w = wred[i];
                    bcast = w;
                    sel_idx_s[t] = (int)(~(uint32_t)(w & 0xFFFFFFFFu));
                    sel_valid_s[t] = 1;
                }
                __syncthreads();
                prev = bcast;
            }
        }
    }
    __syncthreads();

    // dead fallback: <50 peaks -> ascending non-peak indices; none -> center
    if (tid == 0 && target < NSTORM) {
        const float* vb = vil + ((size_t)b * TFRAMES + (TFRAMES - 1)) * (HV * WV);
        int f = 0;
        for (int t = target; t < NSTORM; ++t) {
            while (f < HV * WV && is_peak(vb, f)) ++f;
            sel_idx_s[t] = f; sel_valid_s[t] = 0; ++f;
        }
        if (n == 0) { sel_idx_s[0] = (HV / 2) * WV + (WV / 2); sel_valid_s[0] = 1; }
    }
    __syncthreads();

    // positions / valid outputs + cache feature linear index
    if (tid < NSTORM) {
        int idx = sel_idx_s[tid], vld = sel_valid_s[tid];
        int y = idx / WV, x = idx % WV;
        int yf = y >> 2; if (yf > HF - 1) yf = HF - 1;
        int xf = x >> 2; if (xf > WF - 1) xf = WF - 1;
        lin_s[tid] = yf * WF + xf;
        float* pos_out   = out + (size_t)NB * NSTORM * NC;
        float* valid_out = pos_out + (size_t)NB * NSTORM * 2;
        pos_out[(b * NSTORM + tid) * 2 + 0] = (float)yf;
        pos_out[(b * NSTORM + tid) * 2 + 1] = (float)xf;
        valid_out[b * NSTORM + tid] = vld ? 1.f : 0.f;
    }
    __syncthreads();

    // ---- gather: g[m][c] = features[b][c][lin(m)]  (6400 scattered loads)
    for (int q = tid; q < NSTORM * NC; q += 256) {
        int m = q >> 7, c = q & 127;
        g[m][c] = features[((size_t)b * NC + c) * (HF * WF) + lin_s[m]];
    }
    __syncthreads();

    // ---- matvec: thread = (dim d, storm half); w row streamed from L1,
    // g reads are LDS broadcasts across the 128 d-threads.
    int d = tid & 127, half = tid >> 7;
    const float4* w4 = (const float4*)(proj_w + (size_t)d * NC);
    float bias = proj_b[d];
    for (int m = half * (NSTORM / 2); m < (half + 1) * (NSTORM / 2); ++m) {
        const float4* g4 = (const float4*)g[m];
        float acc = 0.f;
        for (int q = 0; q < 32; ++q) {
            float4 wv = w4[q];
            float4 gv = g4[q];
            acc += gv.x * wv.x;
            acc += gv.y * wv.y;
            acc += gv.z * wv.z;
            acc += gv.w * wv.w;
        }
        out[((size_t)b * NSTORM + m) * NC + d] =
            sel_valid_s[m] ? (acc + bias) : 0.f;
    }
}

extern "C" void kernel_launch(void* const* d_in, const int* in_sizes, int n_in,
                              void* d_out, int out_size, void* d_ws, size_t ws_size,
                              hipStream_t stream) {
    const float* features = (const float*)d_in[0];
    const float* vil      = (const float*)d_in[1];
    const float* proj_w   = (const float*)d_in[2];
    const float* proj_b   = (const float*)d_in[3];
    float* out = (float*)d_out;

    uint8_t* ws = (uint8_t*)d_ws;
    int* tcnt      = (int*)ws;                        // 32*72 ints, all written
    uint64_t* cand = (uint64_t*)(ws + 32768);         // 32*72*256 u64 = 4.7 MB

    dim3 gA(GX, GY, NB);                   // 6 x 12 x 32
    peak_kernel<<<gA, 256, 0, stream>>>(vil, cand, tcnt);
    select_project_kernel<<<NB, 256, 0, stream>>>(cand, tcnt, vil, features,
                                                  proj_w, proj_b, out);
}

// Round 11
// 68.035 us; speedup vs baseline: 4.8103x; 3.1132x over previous
//
#include <hip/hip_runtime.h>
#include <stdint.h>

#define HV 384
#define WV 384
#define HF 96
#define WF 96
#define NC 128
#define NB 32
#define NSTORM 50
#define TFRAMES 12
#define MIN_INT 0.3f

// peak tile geometry
#define TW 64
#define TH 32
#define GX (WV / TW)          // 6
#define GY (HV / TH)          // 12
#define GT (GX * GY)          // 72 tiles per batch
#define LCAP 256              // >= provable max peaks per tile (~153)

// selection
#define CCAP 1024             // collect buffer (expected ~80 used)
// projection
#define SPB 5
#define NGRP (NSTORM / SPB)   // 10 groups per batch
#define NPROJ (NB * NGRP)     // 320 blocks

__device__ __forceinline__ int reflect_idx(int g, int n) {
    if (g < 0) return -g - 1;
    if (g >= n) return 2 * n - 1 - g;
    return g;
}

// ---- slow scalar peak predicate, used only on the dead fallback path
__device__ __forceinline__ bool is_peak(const float* __restrict__ vb, int p) {
    int i = p / WV, j = p % WV;
    float v = vb[p];
    if (!(v > MIN_INT)) return false;
    for (int dr = -4; dr <= 3; ++dr) {
        const float* row = vb + reflect_idx(i + dr, HV) * WV;
        for (int dc = -4; dc <= 3; ++dc)
            if (row[reflect_idx(j + dc, WV)] > v) return false;
    }
    return true;
}

// ---- kernel 1: separable 8x8 max filter on LDS tiles; float4 staging;
// per-tile candidate slots (no global atomics, no memset — every tcnt slot
// is written every launch). key = (float_bits(v) << 32) | ~idx — strict
// total order -> deterministic selection regardless of compaction order.
__global__ void peak_kernel(const float* __restrict__ vil,
                            uint64_t* __restrict__ cand,
                            int* __restrict__ tcnt) {
    __shared__ __align__(16) float A[TH + 7][TW + 8];  // tile + halo
    __shared__ float Bm[TH + 7][TW];                   // horizontal max
    __shared__ uint64_t lkeys[LCAP];
    __shared__ int lcnt;

    int b = blockIdx.z, bx = blockIdx.x;
    int tx0 = bx * TW, ty0 = blockIdx.y * TH;
    int tile = blockIdx.y * GX + bx;
    int tid = threadIdx.x;                 // 256 threads
    const float* vb = vil + ((size_t)b * TFRAMES + (TFRAMES - 1)) * (HV * WV);

    if (tid == 0) lcnt = 0;

    // float4 staging; row reflect is pointer-only, keeps 16B alignment.
    int c0   = (bx == 0) ? 0 : tx0 - 4;               // multiple of 4
    int nf4  = (bx == 0 || bx == GX - 1) ? 17 : 18;
    int aoff = c0 - (tx0 - 4);                        // 0 or 4
    for (int k = tid; k < (TH + 7) * nf4; k += 256) {
        int r = k / nf4, q = k - r * nf4;
        int gr = reflect_idx(ty0 + r - 4, HV);
        float4 vv = *(const float4*)(vb + (size_t)gr * WV + c0 + 4 * q);
        *(float4*)&A[r][aoff + 4 * q] = vv;
    }
    int nl = aoff;
    int rstart = aoff + 4 * nf4;
    int nr = 71 - rstart; if (nr < 0) nr = 0;
    int ns = nl + nr;
    if (ns) for (int k = tid; k < (TH + 7) * ns; k += 256) {
        int r = k / ns, s = k - r * ns;
        int c = (s < nl) ? s : rstart + (s - nl);
        int gr = reflect_idx(ty0 + r - 4, HV);
        int gc = reflect_idx(tx0 + c - 4, WV);
        A[r][c] = vb[(size_t)gr * WV + gc];
    }
    __syncthreads();

    // horizontal: Bm[r][c] = max(A[r][c..c+7])
    for (int k = tid; k < (TH + 7) * TW; k += 256) {
        int r = k / TW, c = k % TW;
        float m = A[r][c];
        #pragma unroll
        for (int d = 1; d < 8; ++d) m = fmaxf(m, A[r][c + d]);
        Bm[r][c] = m;
    }
    __syncthreads();

    // vertical + predicate
    for (int k = tid; k < TH * TW; k += 256) {
        int r = k / TW, c = k % TW;
        float v = A[r + 4][c + 4];
        if (v > MIN_INT) {
            float m = Bm[r][c];
            #pragma unroll
            for (int d = 1; d < 8; ++d) m = fmaxf(m, Bm[r + d][c]);
            if (m <= v) {                  // window max == v -> peak
                int p = (ty0 + r) * WV + (tx0 + c);
                uint64_t key = ((uint64_t)__float_as_uint(v) << 32)
                             | (uint64_t)(0xFFFFFFFFu - (uint32_t)p);
                int pos = atomicAdd(&lcnt, 1);        // LDS atomic only
                if (pos < LCAP) lkeys[pos] = key;
            }
        }
    }
    __syncthreads();

    int take = lcnt < LCAP ? lcnt : LCAP;
    if (tid == 0) tcnt[b * GT + tile] = take;
    uint64_t* dst = cand + (size_t)(b * GT + tile) * LCAP;
    for (int k = tid; k < take; k += 256) dst[k] = lkeys[k];
}

// ---- kernel 2: 320 blocks; block = (batch b, storm-group grp of 5).
// Each block REDUNDANTLY computes its batch's top-50 (identical inputs ->
// identical result; 10 blocks/batch, keys L2-hot after first reader), then
// projects its 5 storms. Keeps full device parallelism (R10's 32-block
// fusion ran at 1.4% occupancy), with only 2 dispatches total.
__global__ void select_project_kernel(const uint64_t* __restrict__ cand,
                                      const int* __restrict__ tcnt,
                                      const float* __restrict__ vil,
                                      const float* __restrict__ features,
                                      const float* __restrict__ proj_w,
                                      const float* __restrict__ proj_b,
                                      float* __restrict__ out) {
    __shared__ uint64_t coll[CCAP];            // 8 KB
    __shared__ int hist[256];
    __shared__ int rss[256];                   // reversed suffix scan
    __shared__ int sc[128];
    __shared__ int offs[GT + 1];
    __shared__ int sel_idx_s[NSTORM];
    __shared__ int sel_valid_s[NSTORM];
    __shared__ int jstar_s, ccnt;
    __shared__ uint64_t wred[4];
    __shared__ uint64_t bcast;
    __shared__ __align__(16) float g[SPB][NC]; // 2.5 KB

    int blk = blockIdx.x;
    int b = blk / NGRP;
    int grp = blk % NGRP;
    int tid = threadIdx.x;                     // 256
    const uint64_t* cb = cand + (size_t)b * GT * LCAP;

    // ---- select: scan of 72 tile counts
    int cval = (tid < GT) ? tcnt[b * GT + tid] : 0;
    if (tid < 128) sc[tid] = cval;
    hist[tid] = 0;
    if (tid == 0) ccnt = 0;
    __syncthreads();
    #pragma unroll
    for (int off = 1; off < 128; off <<= 1) {
        int v = 0;
        if (tid < 128 && tid >= off) v = sc[tid - off];
        __syncthreads();
        if (tid < 128) sc[tid] += v;
        __syncthreads();
    }
    if (tid == 0) offs[0] = 0;
    if (tid < GT) offs[tid + 1] = sc[tid];
    __syncthreads();
    int n = offs[GT];
    int target = n < NSTORM ? n : NSTORM;

    if (n > 0) {
        // pass 1: histogram of top-16-bit value bins (monotone in key)
        for (int gi = tid; gi < n; gi += 256) {
            int lo = 0, hi = GT;
            while (hi - lo > 1) { int mid = (lo + hi) >> 1;
                                  if (offs[mid] <= gi) lo = mid; else hi = mid; }
            uint64_t key = cb[(size_t)lo * LCAP + (gi - offs[lo])];
            int bin = (int)(uint32_t)((key >> 48)) - 0x3E99;
            bin = (bin < 0) ? 0 : (bin > 255 ? 255 : bin);
            atomicAdd(&hist[bin], 1);
        }
        __syncthreads();
        rss[tid] = hist[255 - tid];
        __syncthreads();
        #pragma unroll
        for (int off = 1; off < 256; off <<= 1) {
            int v = (tid >= off) ? rss[tid - off] : 0;
            __syncthreads();
            rss[tid] += v;
            __syncthreads();
        }
        {   // j* = max j with S[j] >= target
            int S_j  = rss[255 - tid];
            int S_j1 = (tid == 255) ? 0 : rss[254 - tid];
            if (S_j >= target && S_j1 < target) jstar_s = tid;
        }
        __syncthreads();
        int jstar = jstar_s;
        // pass 2: collect keys in bins >= j* (expected ~80)
        for (int gi = tid; gi < n; gi += 256) {
            int lo = 0, hi = GT;
            while (hi - lo > 1) { int mid = (lo + hi) >> 1;
                                  if (offs[mid] <= gi) lo = mid; else hi = mid; }
            uint64_t key = cb[(size_t)lo * LCAP + (gi - offs[lo])];
            int bin = (int)(uint32_t)((key >> 48)) - 0x3E99;
            bin = (bin < 0) ? 0 : (bin > 255 ? 255 : bin);
            if (bin >= jstar) {
                int pos = atomicAdd(&ccnt, 1);
                if (pos < CCAP) coll[pos] = key;
            }
        }
        __syncthreads();
        int m = ccnt < CCAP ? ccnt : CCAP;

        if (ccnt <= CCAP) {
            // rank each collected key (keys unique -> unique ranks)
            for (int i = tid; i < m; i += 256) {
                uint64_t ki = coll[i];
                int r = 0;
                for (int j = 0; j < m; ++j) r += (coll[j] > ki);
                if (r < target) {
                    sel_idx_s[r] = (int)(~(uint32_t)(ki & 0xFFFFFFFFu));
                    sel_valid_s[r] = 1;
                }
            }
        } else {
            // dead safety path (collect overflow): iterative rescan
            uint64_t prev = ~0ull;
            for (int t = 0; t < target; ++t) {
                uint64_t best = 0;
                for (int gi = tid; gi < n; gi += 256) {
                    int lo = 0, hi = GT;
                    while (hi - lo > 1) { int mid = (lo + hi) >> 1;
                                          if (offs[mid] <= gi) lo = mid; else hi = mid; }
                    uint64_t key = cb[(size_t)lo * LCAP + (gi - offs[lo])];
                    if (key < prev && key > best) best = key;
                }
                #pragma unroll
                for (int off = 32; off > 0; off >>= 1) {
                    uint64_t o = __shfl_xor(best, off);
                    if (o > best) best = o;
                }
                if ((tid & 63) == 0) wred[tid >> 6] = best;
                __syncthreads();
                if (tid == 0) {
                    uint64_t w = wred[0];
                    #pragma unroll
                    for (int i = 1; i < 4; ++i) if (wred[i] > w) w = wred[i];
                    bcast = w;
                    sel_idx_s[t] = (int)(~(uint32_t)(w & 0xFFFFFFFFu));
                    sel_valid_s[t] = 1;
                }
                __syncthreads();
                prev = bcast;
            }
        }
    }
    __syncthreads();

    // dead fallback: <50 peaks -> ascending non-peak indices; none -> center
    if (tid == 0 && target < NSTORM) {
        const float* vb = vil + ((size_t)b * TFRAMES + (TFRAMES - 1)) * (HV * WV);
        int f = 0;
        for (int t = target; t < NSTORM; ++t) {
            while (f < HV * WV && is_peak(vb, f)) ++f;
            sel_idx_s[t] = f; sel_valid_s[t] = 0; ++f;
        }
        if (n == 0) { sel_idx_s[0] = (HV / 2) * WV + (WV / 2); sel_valid_s[0] = 1; }
    }
    __syncthreads();

    // positions / valid written once per batch (group 0 only)
    if (grp == 0 && tid < NSTORM) {
        int idx = sel_idx_s[tid], vld = sel_valid_s[tid];
        int y = idx / WV, x = idx % WV;
        int yf = y >> 2; if (yf > HF - 1) yf = HF - 1;
        int xf = x >> 2; if (xf > WF - 1) xf = WF - 1;
        float* pos_out   = out + (size_t)NB * NSTORM * NC;
        float* valid_out = pos_out + (size_t)NB * NSTORM * 2;
        pos_out[(b * NSTORM + tid) * 2 + 0] = (float)yf;
        pos_out[(b * NSTORM + tid) * 2 + 1] = (float)xf;
        valid_out[b * NSTORM + tid] = vld ? 1.f : 0.f;
    }

    // ---- project my 5 storms: gather (all 256 threads) + matvec (128)
    for (int q = tid; q < SPB * NC; q += 256) {
        int s = q >> 7, c = q & 127;
        int idx = sel_idx_s[grp * SPB + s];
        int y = idx / WV, x = idx % WV;
        int yf = y >> 2; if (yf > HF - 1) yf = HF - 1;
        int xf = x >> 2; if (xf > WF - 1) xf = WF - 1;
        g[s][c] = features[((size_t)b * NC + c) * (HF * WF) + yf * WF + xf];
    }
    __syncthreads();

    if (tid < NC) {
        int d = tid;
        const float4* w4 = (const float4*)(proj_w + (size_t)d * NC);
        float acc[SPB] = {0.f, 0.f, 0.f, 0.f, 0.f};
        for (int q = 0; q < 32; ++q) {
            float4 wv = w4[q];
            #pragma unroll
            for (int s = 0; s < SPB; ++s) {
                float4 gv = *(const float4*)&g[s][4 * q];
                acc[s] += gv.x * wv.x;
                acc[s] += gv.y * wv.y;
                acc[s] += gv.z * wv.z;
                acc[s] += gv.w * wv.w;
            }
        }
        float bias = proj_b[d];
        #pragma unroll
        for (int s = 0; s < SPB; ++s) {
            int m = grp * SPB + s;
            out[((size_t)b * NSTORM + m) * NC + d] =
                sel_valid_s[m] ? (acc[s] + bias) : 0.f;
        }
    }
}

extern "C" void kernel_launch(void* const* d_in, const int* in_sizes, int n_in,
                              void* d_out, int out_size, void* d_ws, size_t ws_size,
                              hipStream_t stream) {
    const float* features = (const float*)d_in[0];
    const float* vil      = (const float*)d_in[1];
    const float* proj_w   = (const float*)d_in[2];
    const float* proj_b   = (const float*)d_in[3];
    float* out = (float*)d_out;

    uint8_t* ws = (uint8_t*)d_ws;
    int* tcnt      = (int*)ws;                        // 32*72 ints, all written
    uint64_t* cand = (uint64_t*)(ws + 32768);         // 32*72*256 u64 = 4.7 MB

    dim3 gA(GX, GY, NB);                   // 6 x 12 x 32
    peak_kernel<<<gA, 256, 0, stream>>>(vil, cand, tcnt);
    select_project_kernel<<<NPROJ, 256, 0, stream>>>(cand, tcnt, vil, features,
                                                     proj_w, proj_b, out);
}